// Round 5
// baseline (324.765 us; speedup 1.0000x reference)
//
#include <hip/hip_runtime.h>
#include <hip/hip_bf16.h>
#include <math.h>

// B=32, S=2048, D=1024, H=8, D_HEAD=32, D_HEAD_OUT=128, M=65536
#define S_  2048
#define D_  1024

typedef __attribute__((ext_vector_type(8))) short short8;
typedef __attribute__((ext_vector_type(4))) float f32x4;

static __device__ __forceinline__ short f2bf(float x) {
    return __builtin_bit_cast(short, __float2bfloat16(x));   // HW v_cvt, RTNE
}
static __device__ __forceinline__ float bf2f(unsigned short s) {
    unsigned int u = ((unsigned int)s) << 16;
    return __builtin_bit_cast(float, u);
}

__device__ __forceinline__ void gl_lds16(const void* g, void* l) {
    __builtin_amdgcn_global_load_lds(
        (const __attribute__((address_space(1))) unsigned int*)g,
        (__attribute__((address_space(3))) unsigned int*)l, 16, 0, 0);
}

// ---------------------------------------------------------------------------
// Pack w1 (fp32 [8][1024][32]) -> MFMA B-frag order bf16:
//   w1p[((ks*16+cf)*64+lane)*8+r]; col=cf*16+(lane&15) (=h*32+e),
//   k=ks*32+(lane>>4)*8+r (=d)
__global__ void prep_w1(const float* __restrict__ w1, short* __restrict__ w1p) {
    int tid = blockIdx.x * 256 + threadIdx.x;   // 32768 threads
    int lane = tid & 63;
    int fragid = tid >> 6;
    int cf = fragid & 15, ks = fragid >> 4;
    int col = cf * 16 + (lane & 15);
    int h = col >> 5, e = col & 31;
    int d0 = ks * 32 + (lane >> 4) * 8;
    short8 v;
#pragma unroll
    for (int r = 0; r < 8; ++r)
        v[r] = f2bf(w1[((size_t)h * D_ + (d0 + r)) * 32 + e]);
    *(short8*)(w1p + (size_t)tid * 8) = v;
}

// Pack w2 (fp32 [8][32][128]) -> B-frag order bf16:
//   w2p[((h*8+cf2)*64+lane)*8+r]; col=o=cf2*16+(lane&15), k=e=(lane>>4)*8+r
__global__ void prep_w2(const float* __restrict__ w2, short* __restrict__ w2p) {
    int tid = blockIdx.x * 256 + threadIdx.x;   // 4096 threads
    int lane = tid & 63;
    int fragid = tid >> 6;
    int cf2 = fragid & 7, h = fragid >> 3;
    int o = cf2 * 16 + (lane & 15);
    int e0 = (lane >> 4) * 8;
    short8 v;
#pragma unroll
    for (int r = 0; r < 8; ++r)
        v[r] = f2bf(w2[((size_t)h * 32 + (e0 + r)) * 128 + o]);
    *(short8*)(w2p + (size_t)tid * 8) = v;
}

// ---------------------------------------------------------------------------
// gemm1: hact[m][0..256) = gelu(feat @ w1 + b1), bf16 row-major.
// BM=256: grid 256 blocks x 512 threads (8 waves). Wave wv owns rows
// wv*32+[0,32) x ALL 256 cols (acc 2x16 f32x4 = 128 VGPR). Per kstep per
// block: A 32 KB (no duplication) + B-stage 16 KB. Issued vmem total
// ~416 MB vs 1 GB for the R4 BM=64 version.
__global__ void gemm1(
        const float* __restrict__ feat,
        const short* __restrict__ w1p,
        const float* __restrict__ b1,
        short* __restrict__ hact)
{
    __shared__ __align__(16) char lds[34816];
    short* Bbuf = (short*)lds;                 // [2][8192] shorts (32 KB)
    short* hstage = (short*)lds;               // [64][264] bf16 (aliases Bbuf)

    const int tid = threadIdx.x;               // 0..511
    const int wv = tid >> 6;                   // 0..7
    const int lane = tid & 63;
    const int lr = lane & 15;
    const int lg = lane >> 4;
    const size_t m0 = (size_t)blockIdx.x * 256;

    const f32x4* Arow0 = (const f32x4*)(feat + (m0 + (size_t)(wv * 32 + lr)) * D_);
    const f32x4* Arow1 = (const f32x4*)(feat + (m0 + (size_t)(wv * 32 + 16 + lr)) * D_);

    const f32x4 vzero = {0.f, 0.f, 0.f, 0.f};
    f32x4 acc[2][16];
#pragma unroll
    for (int i = 0; i < 2; ++i)
#pragma unroll
        for (int j = 0; j < 16; ++j) acc[i][j] = vzero;

    auto stageB = [&](int buf_, int ks_) {
#pragma unroll
        for (int j = 0; j < 2; ++j)
            gl_lds16(w1p + (size_t)ks_ * 8192 + (size_t)(j * 512 + tid) * 8,
                     Bbuf + buf_ * 8192 + (j * 512 + wv * 64) * 8);
    };

    // A prefetch registers (named, never runtime-indexed)
    f32x4 p0, p1, p2, p3;
    auto loadA = [&](int ks_) {
        const int o = ks_ * 8 + lg * 2;
        p0 = Arow0[o]; p1 = Arow0[o + 1];
        p2 = Arow1[o]; p3 = Arow1[o + 1];
    };

    stageB(0, 0);
    loadA(0);
    __syncthreads();

    for (int ks = 0; ks < 32; ++ks) {
        if (ks < 31) stageB((ks & 1) ^ 1, ks + 1);
        // consume prefetch -> bf16 frags
        short8 af0, af1;
        af0[0] = f2bf(p0.x); af0[1] = f2bf(p0.y); af0[2] = f2bf(p0.z); af0[3] = f2bf(p0.w);
        af0[4] = f2bf(p1.x); af0[5] = f2bf(p1.y); af0[6] = f2bf(p1.z); af0[7] = f2bf(p1.w);
        af1[0] = f2bf(p2.x); af1[1] = f2bf(p2.y); af1[2] = f2bf(p2.z); af1[3] = f2bf(p2.w);
        af1[4] = f2bf(p3.x); af1[5] = f2bf(p3.y); af1[6] = f2bf(p3.z); af1[7] = f2bf(p3.w);
        if (ks < 31) loadA(ks + 1);

        const short8* Bf = (const short8*)(Bbuf + (ks & 1) * 8192);
#pragma unroll
        for (int cf = 0; cf < 16; ++cf) {
            short8 bfr = Bf[cf * 64 + lane];
            acc[0][cf] = __builtin_amdgcn_mfma_f32_16x16x32_bf16(af0, bfr, acc[0][cf], 0, 0, 0);
            acc[1][cf] = __builtin_amdgcn_mfma_f32_16x16x32_bf16(af1, bfr, acc[1][cf], 0, 0, 0);
        }
        __syncthreads();   // drains stage(k+1)+A(k+1); protects buffer reuse
    }

    // epilogue: +b1, exact-erf gelu; 4 passes of 64 rows through LDS staging.
    // C/D frag layout: col = lane&15, row = (lane>>4)*4 + r.
    for (int p = 0; p < 4; ++p) {
        if ((wv >> 1) == p) {
            const int half = wv & 1;                 // rows half*32 + a*16 + ...
#pragma unroll
            for (int cf = 0; cf < 16; ++cf) {
                const int col = cf * 16 + lr;
                const float bias = b1[col];
#pragma unroll
                for (int a = 0; a < 2; ++a)
#pragma unroll
                for (int r = 0; r < 4; ++r) {
                    const int lrow = half * 32 + a * 16 + lg * 4 + r;
                    float x = acc[a][cf][r] + bias;
                    float g = 0.5f * x * (1.0f + erff(x * 0.70710678118654752f));
                    hstage[lrow * 264 + col] = f2bf(g);
                }
            }
        }
        __syncthreads();
#pragma unroll
        for (int it = 0; it < 4; ++it) {
            const int idx = it * 512 + tid;
            const int row = idx >> 5;
            const int c8 = idx & 31;
            short8 v = *(const short8*)(hstage + row * 264 + c8 * 8);
            *(short8*)(hact + (m0 + (size_t)(p * 64 + row)) * 256 + c8 * 8) = v;
        }
        __syncthreads();
    }
}

// ---------------------------------------------------------------------------
// gemm2w: per 16-row tile: logits = hact @ w2 + b2 ; E = exp(logits) ;
// partials pnum/pden[tile][col] = sum over 16 rows of {feat*E, E}.
// Block 256 thr; wave wv handles heads {2wv, 2wv+1} (logit cols wv*256..+256).
__global__ __launch_bounds__(256) void gemm2w(
        const short* __restrict__ hact,
        const float* __restrict__ feat,
        const short* __restrict__ w2p,
        const float* __restrict__ b2,
        float* __restrict__ pnum,
        float* __restrict__ pden)
{
    __shared__ __align__(16) char lds[41216];
    short* hstage = (short*)lds;                         // [16][256] linear, 8 KB
    unsigned short* Est = (unsigned short*)(lds + 8192); // [16][1032] bf16

    const int tid = threadIdx.x;
    const int wv = tid >> 6;
    const int lane = tid & 63;
    const int lr = lane & 15;
    const int lg = lane >> 4;
    const size_t m0 = (size_t)blockIdx.x * 16;

    // stage 16x256 bf16 hact tile (linear: matches gl_lds16 lane order)
#pragma unroll
    for (int j = 0; j < 2; ++j)
        gl_lds16(hact + m0 * 256 + (size_t)(j * 256 + tid) * 8,
                 hstage + (j * 256 + wv * 64) * 8);

    float bias2[16];
#pragma unroll
    for (int cf = 0; cf < 16; ++cf)
        bias2[cf] = b2[(2 * wv + (cf >> 3)) * 128 + (cf & 7) * 16 + lr];

    __syncthreads();

    // GEMM2 (K=32) + exp -> Est
    short8 ah0 = *(const short8*)(hstage + lr * 256 + (2 * wv + 0) * 32 + lg * 8);
    short8 ah1 = *(const short8*)(hstage + lr * 256 + (2 * wv + 1) * 32 + lg * 8);
    const f32x4 vzero = {0.f, 0.f, 0.f, 0.f};
#pragma unroll
    for (int cf = 0; cf < 16; ++cf) {
        const int h = 2 * wv + (cf >> 3);
        short8 bw = *(const short8*)(w2p + ((size_t)(h * 8 + (cf & 7)) * 64 + lane) * 8);
        f32x4 c = vzero;
        c = __builtin_amdgcn_mfma_f32_16x16x32_bf16((cf < 8) ? ah0 : ah1, bw, c, 0, 0, 0);
        const int colL = wv * 256 + (cf >> 3) * 128 + (cf & 7) * 16 + lr;
#pragma unroll
        for (int r = 0; r < 4; ++r) {
            float e = __expf(c[r] + bias2[cf]);   // logits tiny: no max-sub needed
            Est[(lg * 4 + r) * 1032 + colL] = (unsigned short)f2bf(e);
        }
    }
    __syncthreads();

    // weighting: coalesced f32x4 feat read, E from LDS
    const int c0 = tid * 4;
    f32x4 nacc = vzero, dacc = vzero;
    const float* fb = feat + m0 * D_ + c0;
#pragma unroll
    for (int row = 0; row < 16; ++row) {
        f32x4 fv = *(const f32x4*)(fb + (size_t)row * D_);
        unsigned long long ev = *(const unsigned long long*)(Est + row * 1032 + c0);
        f32x4 e;
        e.x = bf2f((unsigned short)(ev));
        e.y = bf2f((unsigned short)(ev >> 16));
        e.z = bf2f((unsigned short)(ev >> 32));
        e.w = bf2f((unsigned short)(ev >> 48));
        dacc += e;
        nacc += fv * e;
    }
    const size_t pb = (size_t)blockIdx.x * 1024 + c0;
    *(f32x4*)(pnum + pb) = nacc;
    *(f32x4*)(pden + pb) = dacc;
}

// ---------------------------------------------------------------------------
// out[b,d] = sum_{j<128} pnum[(b*128+j)*1024+d] / sum_j pden[...]
__global__ __launch_bounds__(256) void finalize3(
        const float* __restrict__ pnum,
        const float* __restrict__ pden,
        float* __restrict__ out)
{
    const int idx = blockIdx.x * 256 + threadIdx.x;   // 32768 = 32*1024
    const int b = idx >> 10;
    const int d = idx & 1023;
    const size_t base = (size_t)b * 128 * 1024 + d;
    float n = 0.f, dn = 0.f;
    for (int j = 0; j < 128; ++j) {
        n  += pnum[base + (size_t)j * 1024];
        dn += pden[base + (size_t)j * 1024];
    }
    out[idx] = n / dn;
}

// ---------------------------------------------------------------------------
extern "C" void kernel_launch(void* const* d_in, const int* in_sizes, int n_in,
                              void* d_out, int out_size, void* d_ws, size_t ws_size,
                              hipStream_t stream) {
    (void)in_sizes; (void)n_in; (void)out_size; (void)ws_size;
    const float* feat = (const float*)d_in[0];
    const float* w1   = (const float*)d_in[1];
    const float* b1   = (const float*)d_in[2];
    const float* w2   = (const float*)d_in[3];
    const float* b2   = (const float*)d_in[4];
    float* out = (float*)d_out;

    char* ws = (char*)d_ws;
    short* hact = (short*)ws;                              // 32 MiB (65536*256 bf16)
    float* pnum = (float*)(ws + (32ull << 20));            // 16 MiB (4096*1024 f32)
    float* pden = (float*)(ws + (48ull << 20));            // 16 MiB
    short* w1p  = (short*)(ws + (64ull << 20));            // 512 KiB
    short* w2p  = (short*)(ws + (64ull << 20) + (512ull << 10));  // 64 KiB

    prep_w1<<<128, 256, 0, stream>>>(w1, w1p);
    prep_w2<<<16, 256, 0, stream>>>(w2, w2p);
    gemm1<<<256, 512, 0, stream>>>(feat, w1p, b1, hact);
    gemm2w<<<4096, 256, 0, stream>>>(hact, feat, w2p, b2, pnum, pden);
    finalize3<<<128, 256, 0, stream>>>(pnum, pden, out);
}

// Round 6
// 211.208 us; speedup vs baseline: 1.5377x; 1.5377x over previous
//
#include <hip/hip_runtime.h>
#include <hip/hip_bf16.h>
#include <math.h>

// B=32, S=2048, D=1024, H=8, D_HEAD=32, D_HEAD_OUT=128, M=65536
#define S_  2048
#define D_  1024

typedef __attribute__((ext_vector_type(8))) short short8;
typedef __attribute__((ext_vector_type(4))) float f32x4;

static __device__ __forceinline__ short f2bf(float x) {
    return __builtin_bit_cast(short, __float2bfloat16(x));   // HW v_cvt, RTNE
}
static __device__ __forceinline__ float bf2f(unsigned short s) {
    unsigned int u = ((unsigned int)s) << 16;
    return __builtin_bit_cast(float, u);
}

__device__ __forceinline__ void gl_lds16(const void* g, void* l) {
    __builtin_amdgcn_global_load_lds(
        (const __attribute__((address_space(1))) unsigned int*)g,
        (__attribute__((address_space(3))) unsigned int*)l, 16, 0, 0);
}

// ---------------------------------------------------------------------------
// Pack w1 (fp32 [8][1024][32]) -> MFMA B-frag order bf16:
//   w1p[((ks*16+cf)*64+lane)*8+r]; col=cf*16+(lane&15) (=h*32+e),
//   k=ks*32+(lane>>4)*8+r (=d)
__global__ void prep_w1(const float* __restrict__ w1, short* __restrict__ w1p) {
    int tid = blockIdx.x * 256 + threadIdx.x;   // 32768 threads
    int lane = tid & 63;
    int fragid = tid >> 6;
    int cf = fragid & 15, ks = fragid >> 4;
    int col = cf * 16 + (lane & 15);
    int h = col >> 5, e = col & 31;
    int d0 = ks * 32 + (lane >> 4) * 8;
    short8 v;
#pragma unroll
    for (int r = 0; r < 8; ++r)
        v[r] = f2bf(w1[((size_t)h * D_ + (d0 + r)) * 32 + e]);
    *(short8*)(w1p + (size_t)tid * 8) = v;
}

// Pack w2 (fp32 [8][32][128]) -> B-frag order bf16:
//   w2p[((h*8+cf2)*64+lane)*8+r]; col=o=cf2*16+(lane&15), k=e=(lane>>4)*8+r
__global__ void prep_w2(const float* __restrict__ w2, short* __restrict__ w2p) {
    int tid = blockIdx.x * 256 + threadIdx.x;   // 4096 threads
    int lane = tid & 63;
    int fragid = tid >> 6;
    int cf2 = fragid & 7, h = fragid >> 3;
    int o = cf2 * 16 + (lane & 15);
    int e0 = (lane >> 4) * 8;
    short8 v;
#pragma unroll
    for (int r = 0; r < 8; ++r)
        v[r] = f2bf(w2[((size_t)h * 32 + (e0 + r)) * 128 + o]);
    *(short8*)(w2p + (size_t)tid * 8) = v;
}

// ---------------------------------------------------------------------------
// gemm1: hact[m][0..256) = gelu(feat @ w1 + b1), bf16 row-major.
// BARRIER-FREE: each wave independently owns 32 rows x 256 cols.
// A read direct from feat (each row once, 128B/row/kstep contiguous).
// B frags read direct from global w1p (512 KB, L2-resident; no LDS staging,
// no __syncthreads anywhere). acc = 2x16 f32x4 = 128 VGPR;
// __launch_bounds__(256,2) -> 256-VGPR cap, no spills (~190 used).
// Epilogue stages through a per-wave-private LDS slice (intra-wave lgkmcnt
// ordering only).
__global__ __launch_bounds__(256, 2) void gemm1(
        const float* __restrict__ feat,
        const short* __restrict__ w1p,
        const float* __restrict__ b1,
        short* __restrict__ hact)
{
    __shared__ short hstage[4][32][264];   // 67.6 KB; per-wave private slices

    const int tid = threadIdx.x;
    const int wv = tid >> 6;
    const int lane = tid & 63;
    const int lr = lane & 15;
    const int lg = lane >> 4;
    const size_t mw = ((size_t)blockIdx.x * 4 + wv) * 32;   // wave's first row

    const f32x4* A0 = (const f32x4*)(feat + (mw + lr) * D_);
    const f32x4* A1 = (const f32x4*)(feat + (mw + 16 + lr) * D_);
    const short8* Bp = (const short8*)w1p;   // [(ks*16+cf)*64 + lane]

    const f32x4 vzero = {0.f, 0.f, 0.f, 0.f};
    f32x4 acc[2][16];
#pragma unroll
    for (int i = 0; i < 2; ++i)
#pragma unroll
        for (int j = 0; j < 16; ++j) acc[i][j] = vzero;

    // A prefetch (named regs, static indexing)
    f32x4 p0 = A0[lg * 2], p1 = A0[lg * 2 + 1];
    f32x4 p2 = A1[lg * 2], p3 = A1[lg * 2 + 1];

    for (int ks = 0; ks < 32; ++ks) {
        short8 af0, af1;
        af0[0] = f2bf(p0.x); af0[1] = f2bf(p0.y); af0[2] = f2bf(p0.z); af0[3] = f2bf(p0.w);
        af0[4] = f2bf(p1.x); af0[5] = f2bf(p1.y); af0[6] = f2bf(p1.z); af0[7] = f2bf(p1.w);
        af1[0] = f2bf(p2.x); af1[1] = f2bf(p2.y); af1[2] = f2bf(p2.z); af1[3] = f2bf(p2.w);
        af1[4] = f2bf(p3.x); af1[5] = f2bf(p3.y); af1[6] = f2bf(p3.z); af1[7] = f2bf(p3.w);
        if (ks < 31) {
            const int o = (ks + 1) * 8 + lg * 2;
            p0 = A0[o]; p1 = A0[o + 1];
            p2 = A1[o]; p3 = A1[o + 1];
        }
        const short8* Bk = Bp + (size_t)ks * 16 * 64 + lane;
#pragma unroll
        for (int cf = 0; cf < 16; ++cf) {
            short8 b = Bk[cf * 64];                  // 1KB coalesced, L2-hit
            acc[0][cf] = __builtin_amdgcn_mfma_f32_16x16x32_bf16(af0, b, acc[0][cf], 0, 0, 0);
            acc[1][cf] = __builtin_amdgcn_mfma_f32_16x16x32_bf16(af1, b, acc[1][cf], 0, 0, 0);
        }
    }

    // epilogue: +b1, exact-erf gelu -> per-wave LDS slice -> coalesced store.
    // C/D frag layout: col = lane&15, row = (lane>>4)*4 + r.
#pragma unroll
    for (int cf = 0; cf < 16; ++cf) {
        const int col = cf * 16 + lr;
        const float bias = b1[col];
#pragma unroll
        for (int a = 0; a < 2; ++a)
#pragma unroll
        for (int r = 0; r < 4; ++r) {
            const int row = a * 16 + lg * 4 + r;
            float x = acc[a][cf][r] + bias;
            float g = 0.5f * x * (1.0f + erff(x * 0.70710678118654752f));
            hstage[wv][row][col] = f2bf(g);
        }
    }
    // intra-wave LDS readback (compiler orders via lgkmcnt; no barrier needed)
#pragma unroll
    for (int it = 0; it < 16; ++it) {
        const int idx = it * 64 + lane;
        const int row = idx >> 5;           // 0..31
        const int c8 = idx & 31;            // 32 chunks of 8 shorts
        short8 v = *(const short8*)(&hstage[wv][row][c8 * 8]);
        *(short8*)(hact + (mw + row) * 256 + c8 * 8) = v;
    }
}

// ---------------------------------------------------------------------------
// gemm2w: per 16-row tile: logits = hact @ w2 + b2 ; E = exp(logits) ;
// partials pnum/pden[tile][col] = sum over 16 rows of {feat*E, E}.
// Block 256 thr; wave wv handles heads {2wv, 2wv+1} (logit cols wv*256..+256).
__global__ __launch_bounds__(256) void gemm2w(
        const short* __restrict__ hact,
        const float* __restrict__ feat,
        const short* __restrict__ w2p,
        const float* __restrict__ b2,
        float* __restrict__ pnum,
        float* __restrict__ pden)
{
    __shared__ __align__(16) char lds[41216];
    short* hstage = (short*)lds;                         // [16][256] linear, 8 KB
    unsigned short* Est = (unsigned short*)(lds + 8192); // [16][1032] bf16

    const int tid = threadIdx.x;
    const int wv = tid >> 6;
    const int lane = tid & 63;
    const int lr = lane & 15;
    const int lg = lane >> 4;
    const size_t m0 = (size_t)blockIdx.x * 16;

    // stage 16x256 bf16 hact tile (linear: matches gl_lds16 lane order)
#pragma unroll
    for (int j = 0; j < 2; ++j)
        gl_lds16(hact + m0 * 256 + (size_t)(j * 256 + tid) * 8,
                 hstage + (j * 256 + wv * 64) * 8);

    float bias2[16];
#pragma unroll
    for (int cf = 0; cf < 16; ++cf)
        bias2[cf] = b2[(2 * wv + (cf >> 3)) * 128 + (cf & 7) * 16 + lr];

    __syncthreads();

    // GEMM2 (K=32) + exp -> Est
    short8 ah0 = *(const short8*)(hstage + lr * 256 + (2 * wv + 0) * 32 + lg * 8);
    short8 ah1 = *(const short8*)(hstage + lr * 256 + (2 * wv + 1) * 32 + lg * 8);
    const f32x4 vzero = {0.f, 0.f, 0.f, 0.f};
#pragma unroll
    for (int cf = 0; cf < 16; ++cf) {
        const int h = 2 * wv + (cf >> 3);
        short8 bw = *(const short8*)(w2p + ((size_t)(h * 8 + (cf & 7)) * 64 + lane) * 8);
        f32x4 c = vzero;
        c = __builtin_amdgcn_mfma_f32_16x16x32_bf16((cf < 8) ? ah0 : ah1, bw, c, 0, 0, 0);
        const int colL = wv * 256 + (cf >> 3) * 128 + (cf & 7) * 16 + lr;
#pragma unroll
        for (int r = 0; r < 4; ++r) {
            float e = __expf(c[r] + bias2[cf]);   // logits tiny: no max-sub needed
            Est[(lg * 4 + r) * 1032 + colL] = (unsigned short)f2bf(e);
        }
    }
    __syncthreads();

    // weighting: coalesced f32x4 feat read, E from LDS
    const int c0 = tid * 4;
    f32x4 nacc = vzero, dacc = vzero;
    const float* fb = feat + m0 * D_ + c0;
#pragma unroll
    for (int row = 0; row < 16; ++row) {
        f32x4 fv = *(const f32x4*)(fb + (size_t)row * D_);
        unsigned long long ev = *(const unsigned long long*)(Est + row * 1032 + c0);
        f32x4 e;
        e.x = bf2f((unsigned short)(ev));
        e.y = bf2f((unsigned short)(ev >> 16));
        e.z = bf2f((unsigned short)(ev >> 32));
        e.w = bf2f((unsigned short)(ev >> 48));
        dacc += e;
        nacc += fv * e;
    }
    const size_t pb = (size_t)blockIdx.x * 1024 + c0;
    *(f32x4*)(pnum + pb) = nacc;
    *(f32x4*)(pden + pb) = dacc;
}

// ---------------------------------------------------------------------------
// out[b,d] = sum_{j<128} pnum[(b*128+j)*1024+d] / sum_j pden[...]
__global__ __launch_bounds__(256) void finalize3(
        const float* __restrict__ pnum,
        const float* __restrict__ pden,
        float* __restrict__ out)
{
    const int idx = blockIdx.x * 256 + threadIdx.x;   // 32768 = 32*1024
    const int b = idx >> 10;
    const int d = idx & 1023;
    const size_t base = (size_t)b * 128 * 1024 + d;
    float n = 0.f, dn = 0.f;
    for (int j = 0; j < 128; ++j) {
        n  += pnum[base + (size_t)j * 1024];
        dn += pden[base + (size_t)j * 1024];
    }
    out[idx] = n / dn;
}

// ---------------------------------------------------------------------------
extern "C" void kernel_launch(void* const* d_in, const int* in_sizes, int n_in,
                              void* d_out, int out_size, void* d_ws, size_t ws_size,
                              hipStream_t stream) {
    (void)in_sizes; (void)n_in; (void)out_size; (void)ws_size;
    const float* feat = (const float*)d_in[0];
    const float* w1   = (const float*)d_in[1];
    const float* b1   = (const float*)d_in[2];
    const float* w2   = (const float*)d_in[3];
    const float* b2   = (const float*)d_in[4];
    float* out = (float*)d_out;

    char* ws = (char*)d_ws;
    short* hact = (short*)ws;                              // 32 MiB (65536*256 bf16)
    float* pnum = (float*)(ws + (32ull << 20));            // 16 MiB (4096*1024 f32)
    float* pden = (float*)(ws + (48ull << 20));            // 16 MiB
    short* w1p  = (short*)(ws + (64ull << 20));            // 512 KiB
    short* w2p  = (short*)(ws + (64ull << 20) + (512ull << 10));  // 64 KiB

    prep_w1<<<128, 256, 0, stream>>>(w1, w1p);
    prep_w2<<<16, 256, 0, stream>>>(w2, w2p);
    gemm1<<<512, 256, 0, stream>>>(feat, w1p, b1, hact);
    gemm2w<<<4096, 256, 0, stream>>>(hact, feat, w2p, b2, pnum, pden);
    finalize3<<<128, 256, 0, stream>>>(pnum, pden, out);
}